// Round 3
// baseline (883.391 us; speedup 1.0000x reference)
//
#include <hip/hip_runtime.h>

#define B_ROWS 4096
#define H_DIM  2048
#define L_DIM  16384
#define TOPK   32
#define CAND_CAP 512

#define GNT 32              // K-tiles of 64: 2048/64

typedef __attribute__((ext_vector_type(8))) short bf16x8;
typedef __attribute__((ext_vector_type(4))) float f32x4;

__device__ __forceinline__ unsigned short f32_to_bf16(float f) {
  unsigned int u = __float_as_uint(f);
  u += 0x7FFFu + ((u >> 16) & 1u);           // round-to-nearest-even
  return (unsigned short)(u >> 16);
}
__device__ __forceinline__ float bf16_to_f32(unsigned short h) {
  return __uint_as_float(((unsigned int)h) << 16);
}

__device__ __forceinline__ void gload_lds16(const void* g, void* l) {
  __builtin_amdgcn_global_load_lds(
      (const __attribute__((address_space(1))) unsigned int*)g,
      (__attribute__((address_space(3))) unsigned int*)l, 16, 0, 0);
}

// ---------------------------------------------------------------- convert f32 -> bf16
__global__ __launch_bounds__(256) void k_convert(const float* __restrict__ src,
                                                 unsigned short* __restrict__ dst, int n4) {
  int i = blockIdx.x * 256 + threadIdx.x;
  if (i < n4) {
    float4 v = ((const float4*)src)[i];
    ushort4 o;
    o.x = f32_to_bf16(v.x); o.y = f32_to_bf16(v.y);
    o.z = f32_to_bf16(v.z); o.w = f32_to_bf16(v.w);
    ((ushort4*)dst)[i] = o;
  }
}

// ------------------------------------------- W_dec [H, L] f32  ->  WdT [L, H] bf16
__global__ __launch_bounds__(256) void k_transpose(const float* __restrict__ Wd,
                                                   unsigned short* __restrict__ WdT) {
  __shared__ float tile[64][65];              // [l_local][h_local], +1 pad
  int bi = blockIdx.x & 255;                  // l tile (16384/64 = 256)
  int bj = blockIdx.x >> 8;                   // h tile (2048/64 = 32)
  int t = threadIdx.x;
  int l0 = bi * 64, h0 = bj * 64;
#pragma unroll
  for (int p = 0; p < 4; ++p) {
    int hr = p * 16 + (t >> 4);
    int lc = (t & 15) * 4;
    float4 v = *(const float4*)(Wd + (size_t)(h0 + hr) * L_DIM + l0 + lc);
    tile[lc + 0][hr] = v.x; tile[lc + 1][hr] = v.y;
    tile[lc + 2][hr] = v.z; tile[lc + 3][hr] = v.w;
  }
  __syncthreads();
#pragma unroll
  for (int p = 0; p < 2; ++p) {
    int lr = p * 32 + (t >> 3);
    int hc = (t & 7) * 8;
    bf16x8 o;
#pragma unroll
    for (int i = 0; i < 8; ++i) o[i] = (short)f32_to_bf16(tile[lr][hc + i]);
    *(bf16x8*)(WdT + (size_t)(l0 + lr) * H_DIM + h0 + hc) = o;
  }
}

// ---------------------------------------------------------------- encoder GEMM (bf16 MFMA)
// A = x_bf16 [4096,2048], Bm = W_enc_bf16 [16384,2048] (K-major), Zp = bf16(relu(A*Bm^T))
// m201-style: 256x256 tile, BK=64, 2-dbuf LDS (128KB), 4 phases/K-tile, K-half stage units,
// counted vmcnt(10) twice per tile. Stage schedule (tile t, buf b=t&1):
//   p0: AK1(t+1)->buf b^1 (free: t-1 consumed)   p1: BK0(t+2)->buf b (b0 reads done @p0)
//   p2: AK0(t+2)->buf b (a reads of K0 done @p1) p3: BK1(t+2)->buf b (b1 reads done @p2)
// Waits: need-before-p0 {AK0,BK0}(t) = 5 units younger -> vmcnt(10) at p3-end;
//        need-before-p2 {AK1,BK1}(t) = 5 units younger -> vmcnt(10) at p1-end.
__global__ __launch_bounds__(512, 2) void k_gemm(const unsigned short* __restrict__ A,
                                                 const unsigned short* __restrict__ Bm,
                                                 unsigned short* __restrict__ Zp) {
  __shared__ unsigned short AL[2][2][8192];   // [buf][khalf][256 rows x 32 shorts] = 64KB
  __shared__ unsigned short BL[2][2][8192];   // 64KB
  const size_t K = H_DIM;
  int bid = blockIdx.x;
  // generation mapping: concurrent wave of 256 blocks = 16 tm x 16 tn; B-panel sharers land
  // on one XCD (bid%8 == tn%8) -> panel L2-resident; A panels L3-resident across gens.
  int tm = (bid >> 4) & 15;
  int tn = ((bid >> 8) << 4) | (bid & 15);
  int t = threadIdx.x;
  int lane = t & 63;
  int w = t >> 6;
  int wm = w >> 2, wn = w & 3;                // 2 x 4 waves; per-wave 128x64 output
  int rloc = lane & 15;
  int kc = lane >> 4;                         // 8-elem K chunk within 32-K half
  int rdoff = ((kc ^ ((rloc >> 1) & 3)) << 3);  // swizzled chunk offset (2-way max)

  // stage decode: thread covers row srow=t>>2 (+128 for 2nd gload), phys chunk t&3
  int srow = t >> 2;
  int c = (t & 3) ^ ((srow >> 1) & 3);        // inverse-permuted global source (rule 21)
  const unsigned short* aS = A  + (size_t)(tm * 256 + srow) * K + c * 8;
  const unsigned short* bS = Bm + (size_t)(tn * 256 + srow) * K + c * 8;
  int dst = t * 8;                            // linear LDS dest (shorts), rows 0-127

  f32x4 acc[8][4];
#pragma unroll
  for (int i = 0; i < 8; ++i)
#pragma unroll
    for (int j = 0; j < 4; ++j) { f32x4 z = {0.f, 0.f, 0.f, 0.f}; acc[i][j] = z; }

#define SA(kt, kh, bf) { size_t o = (size_t)(kt) * 64 + (kh) * 32; \
    gload_lds16(aS + o, &AL[bf][kh][dst]); \
    gload_lds16(aS + 128 * K + o, &AL[bf][kh][4096 + dst]); }
#define SB(kt, kh, bf) { size_t o = (size_t)(kt) * 64 + (kh) * 32; \
    gload_lds16(bS + o, &BL[bf][kh][dst]); \
    gload_lds16(bS + 128 * K + o, &BL[bf][kh][4096 + dst]); }

  const int ab = (wm * 128 + rloc) * 32 + rdoff;
  const int bb = (wn * 64 + rloc) * 32 + rdoff;

#define PHASES(bf, ST0, ST1, ST2, ST3, W1, W3) { \
    bf16x8 aa[4], b0[4], b1[4]; \
    /* p0: K0, m-half0 */ \
    _Pragma("unroll") for (int m = 0; m < 4; ++m) aa[m] = *(const bf16x8*)&AL[bf][0][ab + m * 512]; \
    _Pragma("unroll") for (int n = 0; n < 4; ++n) b0[n] = *(const bf16x8*)&BL[bf][0][bb + n * 512]; \
    ST0; \
    __builtin_amdgcn_s_barrier(); \
    __builtin_amdgcn_s_setprio(1); \
    _Pragma("unroll") for (int m = 0; m < 4; ++m) \
      _Pragma("unroll") for (int n = 0; n < 4; ++n) \
        acc[m][n] = __builtin_amdgcn_mfma_f32_16x16x32_bf16(aa[m], b0[n], acc[m][n], 0, 0, 0); \
    __builtin_amdgcn_s_setprio(0); \
    __builtin_amdgcn_s_barrier(); \
    /* p1: K0, m-half1 */ \
    _Pragma("unroll") for (int m = 0; m < 4; ++m) aa[m] = *(const bf16x8*)&AL[bf][0][ab + (m + 4) * 512]; \
    ST1; \
    __builtin_amdgcn_s_barrier(); \
    __builtin_amdgcn_s_setprio(1); \
    _Pragma("unroll") for (int m = 0; m < 4; ++m) \
      _Pragma("unroll") for (int n = 0; n < 4; ++n) \
        acc[m + 4][n] = __builtin_amdgcn_mfma_f32_16x16x32_bf16(aa[m], b0[n], acc[m + 4][n], 0, 0, 0); \
    __builtin_amdgcn_s_setprio(0); \
    W1; \
    __builtin_amdgcn_s_barrier(); \
    /* p2: K1, m-half0 */ \
    _Pragma("unroll") for (int m = 0; m < 4; ++m) aa[m] = *(const bf16x8*)&AL[bf][1][ab + m * 512]; \
    _Pragma("unroll") for (int n = 0; n < 4; ++n) b1[n] = *(const bf16x8*)&BL[bf][1][bb + n * 512]; \
    ST2; \
    __builtin_amdgcn_s_barrier(); \
    __builtin_amdgcn_s_setprio(1); \
    _Pragma("unroll") for (int m = 0; m < 4; ++m) \
      _Pragma("unroll") for (int n = 0; n < 4; ++n) \
        acc[m][n] = __builtin_amdgcn_mfma_f32_16x16x32_bf16(aa[m], b1[n], acc[m][n], 0, 0, 0); \
    __builtin_amdgcn_s_setprio(0); \
    __builtin_amdgcn_s_barrier(); \
    /* p3: K1, m-half1 */ \
    _Pragma("unroll") for (int m = 0; m < 4; ++m) aa[m] = *(const bf16x8*)&AL[bf][1][ab + (m + 4) * 512]; \
    ST3; \
    __builtin_amdgcn_s_barrier(); \
    __builtin_amdgcn_s_setprio(1); \
    _Pragma("unroll") for (int m = 0; m < 4; ++m) \
      _Pragma("unroll") for (int n = 0; n < 4; ++n) \
        acc[m + 4][n] = __builtin_amdgcn_mfma_f32_16x16x32_bf16(aa[m], b1[n], acc[m + 4][n], 0, 0, 0); \
    __builtin_amdgcn_s_setprio(0); \
    W3; \
    __builtin_amdgcn_s_barrier(); }

  // prologue: units in issue order: BK0(0) AK0(0) BK1(0) AK1(0) BK0(1) AK0(1) BK1(1)
  SB(0, 0, 0) SA(0, 0, 0) SB(0, 1, 0) SA(0, 1, 0) SB(1, 0, 1) SA(1, 0, 1) SB(1, 1, 1)
  asm volatile("s_waitcnt vmcnt(10)" ::: "memory");   // {BK0,AK0}(0) landed
  __builtin_amdgcn_s_barrier();

  for (int kt = 0; kt < GNT - 2; ++kt) {
    int bf = kt & 1, nb = bf ^ 1;
    PHASES(bf,
           SA(kt + 1, 1, nb),
           SB(kt + 2, 0, bf),
           SA(kt + 2, 0, bf),
           SB(kt + 2, 1, bf),
           asm volatile("s_waitcnt vmcnt(10)" ::: "memory"),
           asm volatile("s_waitcnt vmcnt(10)" ::: "memory"));
  }
  // kt = GNT-2 (buf 0): only AK1(GNT-1) left to stage; waits tighten 8 -> 4
  PHASES(0, SA(GNT - 1, 1, 1), , , ,
         asm volatile("s_waitcnt vmcnt(8)" ::: "memory"),
         asm volatile("s_waitcnt vmcnt(4)" ::: "memory"));
  // kt = GNT-1 (buf 1): no stages; drain before K1 reads
  PHASES(1, , , , ,
         asm volatile("s_waitcnt vmcnt(0)" ::: "memory"),
         );
#undef SA
#undef SB
#undef PHASES

  // epilogue: C/D layout col=lane&15, row=(lane>>4)*4+reg [m89]; relu + bf16
  int colg = lane & 15, quad = lane >> 4;
  size_t rbase = (size_t)(tm * 256 + wm * 128 + quad * 4);
  int cbase = tn * 256 + wn * 64 + colg;
#pragma unroll
  for (int m = 0; m < 8; ++m)
#pragma unroll
    for (int n = 0; n < 4; ++n) {
      size_t rr = rbase + m * 16;
      int cc = cbase + n * 16;
#pragma unroll
      for (int r = 0; r < 4; ++r)
        Zp[(rr + r) * L_DIM + cc] = f32_to_bf16(fmaxf(acc[m][n][r], 0.0f));
    }
}

// ---------------------------------------------------------------- candidate selection (bf16 z_pre)
// Histogram v > 2.1625 (44 bins of 0.0625 from 4.85 down) -> smallest edge with cum >= 34;
// collect v > edge - 0.0625. Margin 0.0625 > 2*(bf16-GEMM err 0.013 + bf16 quant 0.016).
__global__ __launch_bounds__(256) void k_select(const unsigned short* __restrict__ zp,
                                                int* __restrict__ cidx, int* __restrict__ ccnt) {
  int b = blockIdx.x;
  const bf16x8* row = (const bf16x8*)(zp + (size_t)b * L_DIM);
  __shared__ unsigned int hist[44];
  __shared__ float s_t;
  __shared__ unsigned int s_cnt;
  int t = threadIdx.x;
  if (t < 44) hist[t] = 0;
  if (t == 0) s_cnt = 0;
  __syncthreads();
  for (int i = t; i < L_DIM / 8; i += 256) {
    bf16x8 v = row[i];
#pragma unroll
    for (int q = 0; q < 8; ++q) {
      float f = bf16_to_f32((unsigned short)v[q]);
      if (f > 2.1625f) {
        int j = (int)floorf((4.85f - f) * 16.0f) + 1;
        j = j < 0 ? 0 : (j > 43 ? 43 : j);
        atomicAdd(&hist[j], 1u);
      }
    }
  }
  __syncthreads();
  if (t == 0) {
    unsigned int cum = 0; float tsel = -1.0f;
    for (int j = 0; j < 44; ++j) {
      cum += hist[j];
      if (cum >= 34) { tsel = 4.85f - 0.0625f * j - 0.0625f; break; }
    }
    s_t = tsel;
  }
  __syncthreads();
  float tsel = s_t;
  if (tsel < 0.0f) {                          // pathological fallback (never for this data)
    float tt = 2.1625f;
    for (int iter = 0; iter < 16 && tsel < 0.0f; ++iter) {
      tt -= 0.25f; if (tt < 0.f) tt = 0.f;
      if (t == 0) s_cnt = 0;
      __syncthreads();
      unsigned int local = 0;
      for (int i = t; i < L_DIM / 8; i += 256) {
        bf16x8 v = row[i];
#pragma unroll
        for (int q = 0; q < 8; ++q) if (bf16_to_f32((unsigned short)v[q]) > tt) local++;
      }
      atomicAdd(&s_cnt, local);
      __syncthreads();
      if (s_cnt >= 34 || tt == 0.f) tsel = tt;
      __syncthreads();
    }
  }
  if (t == 0) s_cnt = 0;
  __syncthreads();
  for (int i = t; i < L_DIM / 8; i += 256) {
    bf16x8 v = row[i];
#pragma unroll
    for (int q = 0; q < 8; ++q) {
      if (bf16_to_f32((unsigned short)v[q]) > tsel) {
        unsigned int p = atomicAdd(&s_cnt, 1u);
        if (p < CAND_CAP) cidx[b * CAND_CAP + p] = i * 8 + q;
      }
    }
  }
  __syncthreads();
  if (t == 0) ccnt[b] = (int)(s_cnt < CAND_CAP ? s_cnt : CAND_CAP);
}

// ------------------------------------- exact rescore of candidates (fp32 inputs, fp64 accum)
__global__ __launch_bounds__(256) void k_recompute(const float* __restrict__ x,
                                                   const float* __restrict__ Wenc,
                                                   const int* __restrict__ cidx,
                                                   const int* __restrict__ ccnt,
                                                   double* __restrict__ cval) {
  int b = blockIdx.x;
  __shared__ float xr[H_DIM];
  int t = threadIdx.x;
  const float4* xv = (const float4*)(x + (size_t)b * H_DIM);
  for (int i = t; i < H_DIM / 4; i += 256) ((float4*)xr)[i] = xv[i];
  __syncthreads();
  int cnt = ccnt[b];
  int wv = t >> 6, lane = t & 63;
  for (int c = wv; c < cnt; c += 4) {
    int l = cidx[b * CAND_CAP + c];
    const float4* wrow = (const float4*)(Wenc + (size_t)l * H_DIM);
    double acc = 0.0;
#pragma unroll
    for (int k8 = 0; k8 < 8; ++k8) {
      float4 w = wrow[k8 * 64 + lane];
      float4 xx = ((const float4*)xr)[k8 * 64 + lane];
      acc += (double)w.x * xx.x + (double)w.y * xx.y + (double)w.z * xx.z + (double)w.w * xx.w;
    }
#pragma unroll
    for (int s = 32; s; s >>= 1) acc += __shfl_xor(acc, s, 64);
    if (lane == 0) cval[b * CAND_CAP + c] = acc;
  }
}

// ------------------------------- top-32 among exact candidates; scatter z; emit (idx,val) list
__global__ __launch_bounds__(64) void k_finalize(const int* __restrict__ cidx,
                                                 const double* __restrict__ cval,
                                                 const int* __restrict__ ccnt,
                                                 float* __restrict__ zout,
                                                 float* __restrict__ selv, int* __restrict__ seli) {
  int b = blockIdx.x;
  int lane = threadIdx.x;
  __shared__ double dv[CAND_CAP];
  __shared__ int di[CAND_CAP];
  int cnt = ccnt[b]; if (cnt > CAND_CAP) cnt = CAND_CAP;
  for (int i = lane; i < cnt; i += 64) { dv[i] = cval[b * CAND_CAP + i]; di[i] = cidx[b * CAND_CAP + i]; }
  __syncthreads();
  for (int s = 0; s < TOPK; ++s) {
    double bv = -1.0e300; int bi = 0x7fffffff;
    for (int i = lane; i < cnt; i += 64) {
      double vi = dv[i]; int ii = di[i];
      if (vi > bv || (vi == bv && ii < bi)) { bv = vi; bi = ii; }
    }
#pragma unroll
    for (int sh = 32; sh; sh >>= 1) {
      double ov = __shfl_xor(bv, sh, 64);
      int oi = __shfl_xor(bi, sh, 64);
      if (ov > bv || (ov == bv && oi < bi)) { bv = ov; bi = oi; }
    }
    bool valid = (s < cnt) && (bv > 0.0);
    if (lane == 0) {
      selv[b * TOPK + s] = valid ? (float)bv : 0.0f;
      seli[b * TOPK + s] = valid ? bi : 0;
      if (valid) zout[(size_t)b * L_DIM + bi] = (float)bv;
    }
    for (int i = lane; i < cnt; i += 64) if (di[i] == bi) dv[i] = -1.0e300;
    __syncthreads();
  }
}

// ---------------------------------------------------------------- sparse decoder
__global__ __launch_bounds__(256) void k_decoder(const unsigned short* __restrict__ WdT,
                                                 const float* __restrict__ selv,
                                                 const int* __restrict__ seli,
                                                 float* __restrict__ xhat) {
  int b = blockIdx.x;
  int t = threadIdx.x;
  __shared__ float sv[TOPK];
  __shared__ int si[TOPK];
  if (t < TOPK) { sv[t] = selv[b * TOPK + t]; si[t] = seli[b * TOPK + t]; }
  __syncthreads();
  float acc[8] = {0.f, 0.f, 0.f, 0.f, 0.f, 0.f, 0.f, 0.f};
  for (int j = 0; j < TOPK; ++j) {
    float vj = sv[j];
    bf16x8 w = *(const bf16x8*)(WdT + (size_t)si[j] * H_DIM + t * 8);
#pragma unroll
    for (int i = 0; i < 8; ++i) acc[i] += vj * bf16_to_f32((unsigned short)w[i]);
  }
  float4 o0 = {acc[0], acc[1], acc[2], acc[3]};
  float4 o1 = {acc[4], acc[5], acc[6], acc[7]};
  float4* op = (float4*)(xhat + (size_t)b * H_DIM + t * 8);
  op[0] = o0; op[1] = o1;
}

extern "C" void kernel_launch(void* const* d_in, const int* in_sizes, int n_in,
                              void* d_out, int out_size, void* d_ws, size_t ws_size,
                              hipStream_t stream) {
  const float* x    = (const float*)d_in[0];
  const float* Wenc = (const float*)d_in[1];
  const float* Wdec = (const float*)d_in[2];
  // d_in[3] = topk (=32), hardcoded

  float* xhat = (float*)d_out;
  float* z    = (float*)d_out + (size_t)B_ROWS * H_DIM;

  char* ws = (char*)d_ws;
  if (ws_size < 177225728u) return;  // need ~169 MB scratch
  unsigned short* xbf    = (unsigned short*)(ws);                 // 16,777,216 B
  unsigned short* Wencbf = (unsigned short*)(ws + 16777216);      // 67,108,864 B
  unsigned short* WdT    = (unsigned short*)(ws + 83886080);      // 67,108,864 B
  int*    cidx = (int*)   (ws + 150994944);                       //  8,388,608 B
  double* cval = (double*)(ws + 159383552);                       // 16,777,216 B
  int*    ccnt = (int*)   (ws + 176160768);                       //     16,384 B
  float*  selv = (float*) (ws + 176177152);                       //    524,288 B
  int*    seli = (int*)   (ws + 176701440);                       //    524,288 B

  unsigned short* zpre = (unsigned short*)z;                      // bf16 scratch in z region

  k_convert<<<(2097152 + 255) / 256, 256, 0, stream>>>(x, xbf, 2097152);
  k_convert<<<(8388608 + 255) / 256, 256, 0, stream>>>(Wenc, Wencbf, 8388608);
  k_transpose<<<8192, 256, 0, stream>>>(Wdec, WdT);
  k_gemm<<<1024, 512, 0, stream>>>(xbf, Wencbf, zpre);            // bf16 relu'd z_pre
  k_select<<<B_ROWS, 256, 0, stream>>>(zpre, cidx, ccnt);
  k_recompute<<<B_ROWS, 256, 0, stream>>>(x, Wenc, cidx, ccnt, cval);
  hipMemsetAsync(z, 0, (size_t)B_ROWS * L_DIM * sizeof(float), stream);
  k_finalize<<<B_ROWS, 64, 0, stream>>>(cidx, cval, ccnt, z, selv, seli);
  k_decoder<<<B_ROWS, 256, 0, stream>>>(WdT, selv, seli, xhat);
}

// Round 4
// 713.597 us; speedup vs baseline: 1.2379x; 1.2379x over previous
//
#include <hip/hip_runtime.h>

#define B_ROWS 4096
#define H_DIM  2048
#define L_DIM  16384
#define TOPK   32
#define CAND_CAP 512
#define AMBIG_CAP 128
#define BAND 0.06f          // 2*e ; e = bf16-path max |v_bf - v_true| (est 0.018, margin 1.67x)

typedef __attribute__((ext_vector_type(8))) short bf16x8;
typedef __attribute__((ext_vector_type(4))) float f32x4;

__device__ __forceinline__ unsigned short f32_to_bf16(float f) {
  unsigned int u = __float_as_uint(f);
  u += 0x7FFFu + ((u >> 16) & 1u);           // round-to-nearest-even
  return (unsigned short)(u >> 16);
}
__device__ __forceinline__ float bf16_to_f32(unsigned short h) {
  return __uint_as_float(((unsigned int)h) << 16);
}

__device__ __forceinline__ void gload_lds16(const void* g, void* l) {
  __builtin_amdgcn_global_load_lds(
      (const __attribute__((address_space(1))) unsigned int*)g,
      (__attribute__((address_space(3))) unsigned int*)l, 16, 0, 0);
}

// ---------------------------------------------------------------- convert f32 -> bf16
__global__ __launch_bounds__(256) void k_convert(const float* __restrict__ src,
                                                 unsigned short* __restrict__ dst, int n4) {
  int i = blockIdx.x * 256 + threadIdx.x;
  if (i < n4) {
    float4 v = ((const float4*)src)[i];
    ushort4 o;
    o.x = f32_to_bf16(v.x); o.y = f32_to_bf16(v.y);
    o.z = f32_to_bf16(v.z); o.w = f32_to_bf16(v.w);
    ((ushort4*)dst)[i] = o;
  }
}

// ------------------------------------------- W_dec [H, L] f32  ->  WdT [L, H] bf16
__global__ __launch_bounds__(256) void k_transpose(const float* __restrict__ Wd,
                                                   unsigned short* __restrict__ WdT) {
  __shared__ float tile[64][65];              // [l_local][h_local], +1 pad
  int bi = blockIdx.x & 255;                  // l tile (16384/64 = 256)
  int bj = blockIdx.x >> 8;                   // h tile (2048/64 = 32)
  int t = threadIdx.x;
  int l0 = bi * 64, h0 = bj * 64;
#pragma unroll
  for (int p = 0; p < 4; ++p) {
    int hr = p * 16 + (t >> 4);
    int lc = (t & 15) * 4;
    float4 v = *(const float4*)(Wd + (size_t)(h0 + hr) * L_DIM + l0 + lc);
    tile[lc + 0][hr] = v.x; tile[lc + 1][hr] = v.y;
    tile[lc + 2][hr] = v.z; tile[lc + 3][hr] = v.w;
  }
  __syncthreads();
#pragma unroll
  for (int p = 0; p < 2; ++p) {
    int lr = p * 32 + (t >> 3);
    int hc = (t & 7) * 8;
    bf16x8 o;
#pragma unroll
    for (int i = 0; i < 8; ++i) o[i] = (short)f32_to_bf16(tile[lr][hc + i]);
    *(bf16x8*)(WdT + (size_t)(l0 + lr) * H_DIM + h0 + hc) = o;
  }
}

// ---------------------------------------------------------------- encoder GEMM (bf16 MFMA)
// R2-proven schedule (3-slot LDS ring, BK=32, counted vmcnt(4)) + R3 generation mapping
// (tn-panel sharers on one XCD -> B panel L2-resident).
__global__ __launch_bounds__(512, 2) void k_gemm(const unsigned short* __restrict__ A,
                                                 const unsigned short* __restrict__ Bm,
                                                 unsigned short* __restrict__ Zp) {
  __shared__ unsigned short As[3 * 8192];     // 3 x 256x32 bf16 = 48 KB
  __shared__ unsigned short Bs[3 * 8192];     // 48 KB
  const size_t K = H_DIM;
  int bid = blockIdx.x;
  // generation mapping: concurrent wave of 256 blocks = 16 tm x 16 tn; bid%8 == tn%8
  int tm = (bid >> 4) & 15;                   // 16 M-tiles
  int tn = ((bid >> 8) << 4) | (bid & 15);    // 64 N-tiles
  int t = threadIdx.x;
  int lane = t & 63;
  int w = t >> 6;
  int wm = w >> 2, wn = w & 3;                // 2 x 4 wave grid; per-wave 128x64

  int rloc = lane & 15;
  int kc = lane >> 4;                         // 0..3 : 8-elem K chunk
  int swzk = (kc ^ ((rloc >> 1) & 3)) << 3;   // bank swizzle (2-way max), shorts

  // staging decode: per thread row = j*128 + (t>>2), phys chunk (t&3) holds logical kcs
  int srow = t >> 2;
  int kcs = (t & 3) ^ ((srow >> 1) & 3);      // inverse-permuted global source (rule 21)
  const unsigned short* aS0 = A + (size_t)(tm * 256 + srow) * K + kcs * 8;
  const unsigned short* aS1 = aS0 + 128 * K;
  const unsigned short* bS0 = Bm + (size_t)(tn * 256 + srow) * K + kcs * 8;
  const unsigned short* bS1 = bS0 + 128 * K;
  int dA = t * 8;                             // linear LDS dest (shorts)

  f32x4 acc[8][4];
#pragma unroll
  for (int i = 0; i < 8; ++i)
#pragma unroll
    for (int j = 0; j < 4; ++j) { f32x4 z = {0.f, 0.f, 0.f, 0.f}; acc[i][j] = z; }

#define STAGE_A(kt, sw) { size_t ko = (size_t)(kt) * 32; \
    gload_lds16(aS0 + ko, &As[(sw) * 8192 + dA]); \
    gload_lds16(aS1 + ko, &As[(sw) * 8192 + 4096 + dA]); }
#define STAGE_B(kt, sw) { size_t ko = (size_t)(kt) * 32; \
    gload_lds16(bS0 + ko, &Bs[(sw) * 8192 + dA]); \
    gload_lds16(bS1 + ko, &Bs[(sw) * 8192 + 4096 + dA]); }

  // prologue: stage tile0 + tile1; wait tile0 (4 outstanding allowed)
  STAGE_A(0, 0) STAGE_B(0, 0)
  STAGE_A(1, 1) STAGE_B(1, 1)
  asm volatile("s_waitcnt vmcnt(4)" ::: "memory");
  __builtin_amdgcn_s_barrier();

  int sR = 0;
  const int aBase0 = (wm * 128 + rloc) * 32 + swzk;
  const int bBase0 = (wn * 64 + rloc) * 32 + swzk;
  const int NKT = H_DIM / 32;
  for (int kt = 0; kt < NKT; ++kt) {
    int sW = sR + 2; if (sW >= 3) sW -= 3;
    const unsigned short* Ab = &As[sR * 8192 + aBase0];
    const unsigned short* Bb = &Bs[sR * 8192 + bBase0];
    bool st = (kt + 2 < NKT);                 // wave-uniform
    // ---- phase 0: read A-half0 + all B frags; issue A-stage of tile kt+2
    bf16x8 a0[4], b0[4];
#pragma unroll
    for (int m = 0; m < 4; ++m) a0[m] = *(const bf16x8*)(Ab + m * 512);
#pragma unroll
    for (int n = 0; n < 4; ++n) b0[n] = *(const bf16x8*)(Bb + n * 512);
    if (st) STAGE_A(kt + 2, sW)
    __builtin_amdgcn_s_barrier();
    __builtin_amdgcn_s_setprio(1);
#pragma unroll
    for (int m = 0; m < 4; ++m)
#pragma unroll
      for (int n = 0; n < 4; ++n)
        acc[m][n] = __builtin_amdgcn_mfma_f32_16x16x32_bf16(a0[m], b0[n], acc[m][n], 0, 0, 0);
    __builtin_amdgcn_s_setprio(0);
    __builtin_amdgcn_s_barrier();
    // ---- phase 1: read A-half1 (B reused); issue B-stage of tile kt+2
    bf16x8 a1[4];
#pragma unroll
    for (int m = 0; m < 4; ++m) a1[m] = *(const bf16x8*)(Ab + (m + 4) * 512);
    if (st) STAGE_B(kt + 2, sW)
    __builtin_amdgcn_s_barrier();
    __builtin_amdgcn_s_setprio(1);
#pragma unroll
    for (int m = 0; m < 4; ++m)
#pragma unroll
      for (int n = 0; n < 4; ++n)
        acc[m + 4][n] = __builtin_amdgcn_mfma_f32_16x16x32_bf16(a1[m], b0[n], acc[m + 4][n], 0, 0, 0);
    __builtin_amdgcn_s_setprio(0);
    // ---- tile boundary: counted wait
    if (kt < NKT - 2) { asm volatile("s_waitcnt vmcnt(4)" ::: "memory"); }
    else if (kt == NKT - 2) { asm volatile("s_waitcnt vmcnt(0)" ::: "memory"); }
    __builtin_amdgcn_s_barrier();
    ++sR; if (sR == 3) sR = 0;
  }
#undef STAGE_A
#undef STAGE_B
  // epilogue: C/D layout col=lane&15, row=(lane>>4)*4+reg [m89]; relu + bf16
  int colg = lane & 15, quad = lane >> 4;
  size_t rbase = (size_t)(tm * 256 + wm * 128 + quad * 4);
  int cbase = tn * 256 + wn * 64 + colg;
#pragma unroll
  for (int m = 0; m < 8; ++m)
#pragma unroll
    for (int n = 0; n < 4; ++n) {
      size_t rr = rbase + m * 16;
      int cc = cbase + n * 16;
#pragma unroll
      for (int r = 0; r < 4; ++r)
        Zp[(rr + r) * L_DIM + cc] = f32_to_bf16(fmaxf(acc[m][n][r], 0.0f));
    }
}

// ------------------------------------- single-pass candidate collect (fixed threshold)
// v32 ~ N(2.89, 0.058) over rows -> thr 2.3 is ~10 sigma safe; expected ~175 cands/row.
// Fallback lowers thr if <40 collected (never taken on this data; keeps correctness).
__global__ __launch_bounds__(256) void k_collect(const unsigned short* __restrict__ zp,
                                                 int* __restrict__ cidx,
                                                 float* __restrict__ cvals,
                                                 int* __restrict__ ccnt) {
  int b = blockIdx.x;
  const bf16x8* row = (const bf16x8*)(zp + (size_t)b * L_DIM);
  __shared__ unsigned int s_cnt;
  int t = threadIdx.x;
  float thr = 2.3f;
  for (int attempt = 0; attempt < 8; ++attempt) {
    if (t == 0) s_cnt = 0;
    __syncthreads();
    for (int i = t; i < L_DIM / 8; i += 256) {
      bf16x8 v = row[i];
#pragma unroll
      for (int q = 0; q < 8; ++q) {
        float f = bf16_to_f32((unsigned short)v[q]);
        if (f > thr) {
          unsigned int p = atomicAdd(&s_cnt, 1u);
          if (p < CAND_CAP) { cidx[b * CAND_CAP + p] = i * 8 + q; cvals[b * CAND_CAP + p] = f; }
        }
      }
    }
    __syncthreads();
    if (s_cnt >= 40 || thr <= 0.0f) break;
    thr -= 0.6f; if (thr < 0.0f) thr = 0.0f;
    __syncthreads();
  }
  if (t == 0) ccnt[b] = (int)(s_cnt < CAND_CAP ? s_cnt : CAND_CAP);
}

// ----------------- fused topk: rank -> classify vs b32 -> fp64-rescore AMBIG only ->
//                   emit final 32 (scatter z + selv/seli for decoder)
// SURE-IN  (v_bf > b32+BAND): provably in true top-32 given |v_bf-v_true| <= BAND/2.
// SURE-OUT (v_bf < b32-BAND): provably out. AMBIG band (~12/row) rescored exactly.
__global__ __launch_bounds__(256) void k_topk(const float* __restrict__ x,
                                              const float* __restrict__ Wenc,
                                              const int* __restrict__ cidx,
                                              const float* __restrict__ cvals,
                                              const int* __restrict__ ccnt,
                                              float* __restrict__ zout,
                                              float* __restrict__ selv,
                                              int* __restrict__ seli) {
  int b = blockIdx.x;
  int t = threadIdx.x;
  __shared__ float xr[H_DIM];                 // 8 KB
  __shared__ float cv[CAND_CAP];
  __shared__ int   ci[CAND_CAP];
  __shared__ float s_b32;
  __shared__ unsigned int s_na, s_nin;
  __shared__ int    ai[AMBIG_CAP];
  __shared__ double ax[AMBIG_CAP];
  int cnt = ccnt[b]; if (cnt > CAND_CAP) cnt = CAND_CAP;

  const float4* xv = (const float4*)(x + (size_t)b * H_DIM);
  for (int i = t; i < H_DIM / 4; i += 256) ((float4*)xr)[i] = xv[i];
  for (int i = t; i < cnt; i += 256) { cv[i] = cvals[b * CAND_CAP + i]; ci[i] = cidx[b * CAND_CAP + i]; }
  if (t == 0) { s_b32 = -1.0f; s_na = 0; s_nin = 0; }
  __syncthreads();

  // rank (tie-break: equal value, lower slot counts as above) -> b32 = rank-31 value
  for (int i = t; i < cnt; i += 256) {
    float vi = cv[i]; int r = 0;
    for (int j = 0; j < cnt; ++j) { float vj = cv[j]; r += (vj > vi) || (vj == vi && j < i); }
    if (r == 31) s_b32 = vi;
  }
  __syncthreads();
  float b32 = s_b32;                          // -1 only if cnt < 32 (pathological)

  // classify AMBIG
  for (int i = t; i < cnt; i += 256) {
    if (b32 >= 0.0f && fabsf(cv[i] - b32) <= BAND) {
      unsigned int p = atomicAdd(&s_na, 1u);
      if (p < AMBIG_CAP) ai[p] = i;
    }
  }
  __syncthreads();
  int na = (int)(s_na < AMBIG_CAP ? s_na : AMBIG_CAP);

  // fp64 rescore of AMBIG candidates (gather fp32 W_enc rows)
  int wv = t >> 6, lane = t & 63;
  for (int a = wv; a < na; a += 4) {
    int l = ci[ai[a]];
    const float4* wrow = (const float4*)(Wenc + (size_t)l * H_DIM);
    double acc = 0.0;
#pragma unroll
    for (int k8 = 0; k8 < 8; ++k8) {
      float4 ww = wrow[k8 * 64 + lane];
      float4 xx = ((const float4*)xr)[k8 * 64 + lane];
      acc += (double)ww.x * xx.x + (double)ww.y * xx.y + (double)ww.z * xx.z + (double)ww.w * xx.w;
    }
#pragma unroll
    for (int s = 32; s; s >>= 1) acc += __shfl_xor(acc, s, 64);
    if (lane == 0) ax[a] = acc;
  }
  __syncthreads();

  // emit SURE-IN (bf16-path value; |err| <= 0.03 << 0.113 threshold)
  for (int i = t; i < cnt; i += 256) {
    float vi = cv[i];
    if (b32 >= 0.0f && vi - b32 > BAND) {
      unsigned int p = atomicAdd(&s_nin, 1u);
      selv[b * TOPK + p] = vi; seli[b * TOPK + p] = ci[i];
      zout[(size_t)b * L_DIM + ci[i]] = vi;
    }
  }
  __syncthreads();
  int s0 = (int)s_nin;                        // <= 31 by construction

  // fill remaining 32-s0 slots from AMBIG by exact fp64 value (one wave, serial extract)
  if (t < 64) {
    int need = TOPK - s0; if (need < 0) need = 0;
    for (int k = 0; k < need; ++k) {
      double bv = -1.0e300; int bidx = 0x7fffffff; int bpos = -1;
      for (int a = lane; a < na; a += 64) {
        double v = ax[a]; int ii = ci[ai[a]];
        if (v > bv || (v == bv && ii < bidx)) { bv = v; bidx = ii; bpos = a; }
      }
#pragma unroll
      for (int sh = 32; sh; sh >>= 1) {
        double ov = __shfl_xor(bv, sh, 64);
        int oi = __shfl_xor(bidx, sh, 64);
        int op = __shfl_xor(bpos, sh, 64);
        if (ov > bv || (ov == bv && oi < bidx)) { bv = ov; bidx = oi; bpos = op; }
      }
      bool valid = (bpos >= 0) && (bv > -1.0e299);
      if (lane == 0) {
        selv[b * TOPK + s0 + k] = valid ? (float)bv : 0.0f;
        seli[b * TOPK + s0 + k] = valid ? bidx : 0;
        if (valid) zout[(size_t)b * L_DIM + bidx] = (float)bv;
      }
      for (int a = lane; a < na; a += 64) if (a == bpos) ax[a] = -1.0e300;
    }
  }
}

// ---------------------------------------------------------------- sparse decoder
__global__ __launch_bounds__(256) void k_decoder(const unsigned short* __restrict__ WdT,
                                                 const float* __restrict__ selv,
                                                 const int* __restrict__ seli,
                                                 float* __restrict__ xhat) {
  int b = blockIdx.x;
  int t = threadIdx.x;
  __shared__ float sv[TOPK];
  __shared__ int si[TOPK];
  if (t < TOPK) { sv[t] = selv[b * TOPK + t]; si[t] = seli[b * TOPK + t]; }
  __syncthreads();
  float acc[8] = {0.f, 0.f, 0.f, 0.f, 0.f, 0.f, 0.f, 0.f};
  for (int j = 0; j < TOPK; ++j) {
    float vj = sv[j];
    bf16x8 w = *(const bf16x8*)(WdT + (size_t)si[j] * H_DIM + t * 8);
#pragma unroll
    for (int i = 0; i < 8; ++i) acc[i] += vj * bf16_to_f32((unsigned short)w[i]);
  }
  float4 o0 = {acc[0], acc[1], acc[2], acc[3]};
  float4 o1 = {acc[4], acc[5], acc[6], acc[7]};
  float4* op = (float4*)(xhat + (size_t)b * H_DIM + t * 8);
  op[0] = o0; op[1] = o1;
}

extern "C" void kernel_launch(void* const* d_in, const int* in_sizes, int n_in,
                              void* d_out, int out_size, void* d_ws, size_t ws_size,
                              hipStream_t stream) {
  const float* x    = (const float*)d_in[0];
  const float* Wenc = (const float*)d_in[1];
  const float* Wdec = (const float*)d_in[2];
  // d_in[3] = topk (=32), hardcoded

  float* xhat = (float*)d_out;
  float* z    = (float*)d_out + (size_t)B_ROWS * H_DIM;

  char* ws = (char*)d_ws;
  if (ws_size < 177225728u) return;  // need ~169 MB scratch
  unsigned short* xbf    = (unsigned short*)(ws);                 // 16,777,216 B
  unsigned short* Wencbf = (unsigned short*)(ws + 16777216);      // 67,108,864 B
  unsigned short* WdT    = (unsigned short*)(ws + 83886080);      // 67,108,864 B
  int*    cidx  = (int*)  (ws + 150994944);                       //  8,388,608 B
  float*  cvals = (float*)(ws + 159383552);                       //  8,388,608 B
  int*    ccnt  = (int*)  (ws + 176160768);                       //     16,384 B
  float*  selv  = (float*)(ws + 176177152);                       //    524,288 B
  int*    seli  = (int*)  (ws + 176701440);                       //    524,288 B

  unsigned short* zpre = (unsigned short*)z;                      // bf16 scratch in z region

  k_convert<<<(2097152 + 255) / 256, 256, 0, stream>>>(x, xbf, 2097152);
  k_convert<<<(8388608 + 255) / 256, 256, 0, stream>>>(Wenc, Wencbf, 8388608);
  k_transpose<<<8192, 256, 0, stream>>>(Wdec, WdT);
  k_gemm<<<1024, 512, 0, stream>>>(xbf, Wencbf, zpre);            // bf16 relu'd z_pre
  k_collect<<<B_ROWS, 256, 0, stream>>>(zpre, cidx, cvals, ccnt);
  hipMemsetAsync(z, 0, (size_t)B_ROWS * L_DIM * sizeof(float), stream);
  k_topk<<<B_ROWS, 256, 0, stream>>>(x, Wenc, cidx, cvals, ccnt, z, selv, seli);
  k_decoder<<<B_ROWS, 256, 0, stream>>>(WdT, selv, seli, xhat);
}